// Round 4
// baseline (4850.000 us; speedup 1.0000x reference)
//
#include <hip/hip_runtime.h>
#include <hip/hip_bf16.h>
#include <math.h>

typedef __hip_bfloat16 bf16;

// Problem dims
#define DD   1024
#define HH   16
#define DHD  64
#define EE   8
#define BB   4
#define LL   512
#define TT   2048
#define DFFD 4096
#define NLAT 2048   // B*L
#define NTOK 8192   // B*T
#define NASG 4096   // 2 * NLAT

__device__ __forceinline__ float toF(float x) { return x; }
__device__ __forceinline__ float toF(bf16 x) { return __bfloat162float(x); }
__device__ __forceinline__ float us2f(unsigned short u) {
    union { unsigned int i; float f; } v; v.i = ((unsigned int)u) << 16; return v.f;
}
__device__ __forceinline__ unsigned short f2us(float f) {
    bf16 t = __float2bfloat16(f);
    return *(unsigned short*)&t;
}

// ---------------- LayerNorm: one block (256 thr) per row, D=1024 --------------
// fp32 in, fp32 scale/shift, bf16 out (internal activation format)
__device__ __forceinline__ float block_sum256(float val, float* red) {
    #pragma unroll
    for (int off = 32; off > 0; off >>= 1) val += __shfl_down(val, off);
    if ((threadIdx.x & 63) == 0) red[threadIdx.x >> 6] = val;
    __syncthreads();
    if (threadIdx.x == 0) red[4] = red[0] + red[1] + red[2] + red[3];
    __syncthreads();
    float r = red[4];
    __syncthreads();   // protect red[] before next reuse
    return r;
}

__global__ __launch_bounds__(256) void ln_kernel(
    const float* __restrict__ x, const float* __restrict__ g, const float* __restrict__ b,
    bf16* __restrict__ out)
{
    __shared__ float red[5];
    int row = blockIdx.x;
    int tid = threadIdx.x;
    const float* xr = x + (size_t)row * DD;
    float v[4];
    #pragma unroll
    for (int i = 0; i < 4; ++i) v[i] = xr[tid + i * 256];
    float s = v[0] + v[1] + v[2] + v[3];
    float mean = block_sum256(s, red) * (1.0f / DD);
    float sq = 0.f;
    #pragma unroll
    for (int i = 0; i < 4; ++i) { float d = v[i] - mean; sq += d * d; }
    float var = block_sum256(sq, red) * (1.0f / DD);
    float rstd = rsqrtf(var + 1e-5f);
    bf16* orow = out + (size_t)row * DD;
    #pragma unroll
    for (int i = 0; i < 4; ++i) {
        int c = tid + i * 256;
        orow[c] = __float2bfloat16((v[i] - mean) * rstd * g[c] + b[c]);
    }
}

// ---------------- Generic GEMM: C[M,N] = A[M,K](bf16) * W[N,K](f32)^T + bias --
// 64x64 tile, BK=16, 256 threads, 4x4 per thread. fp32 accumulate.
// act==1 -> exact gelu; res (f32) residual; gather = A-row indices;
// seg_off/seg_cnt -> grouped-expert mode (blockIdx.z = expert).
// Output: Cb (bf16) or Cf (f32) — exactly one non-null.
__global__ __launch_bounds__(256) void gemm_kernel(
    const bf16* __restrict__ A, const float* __restrict__ W,
    const float* __restrict__ bias,
    bf16* __restrict__ Cb, float* __restrict__ Cf,
    int M, int N, int K,
    const float* __restrict__ res,
    int act,
    const int* __restrict__ gather,
    const int* __restrict__ seg_off, const int* __restrict__ seg_cnt)
{
    int m_base = 0, mrows = M;
    if (seg_off) {
        int e = blockIdx.z;
        m_base = seg_off[e];
        mrows  = seg_cnt[e];
        W    += (size_t)e * N * K;
        bias += (size_t)e * N;
    }
    int m0 = blockIdx.y * 64;
    if (m0 >= mrows) return;
    int n0 = blockIdx.x * 64;

    __shared__ float As[16][68];
    __shared__ float Ws[16][68];

    int tid  = threadIdx.x;
    int la_r = tid >> 2;          // 0..63
    int la_k = (tid & 3) << 2;    // 0,4,8,12

    const bf16* aptr = nullptr;
    bool a_ok = (m0 + la_r) < mrows;
    if (a_ok) {
        int grow = m_base + m0 + la_r;
        int asrc = gather ? gather[grow] : grow;
        aptr = A + (size_t)asrc * K + la_k;
    }
    const float* wptr = W + (size_t)(n0 + la_r) * K + la_k;

    int cx = tid & 15, cy = tid >> 4;
    float acc[4][4] = {};

    for (int k0 = 0; k0 < K; k0 += 16) {
        ushort4 av = make_ushort4(0, 0, 0, 0);
        if (a_ok) av = *(const ushort4*)(aptr + k0);
        float4 wv = *(const float4*)(wptr + k0);
        As[la_k + 0][la_r] = us2f(av.x);
        As[la_k + 1][la_r] = us2f(av.y);
        As[la_k + 2][la_r] = us2f(av.z);
        As[la_k + 3][la_r] = us2f(av.w);
        Ws[la_k + 0][la_r] = wv.x;
        Ws[la_k + 1][la_r] = wv.y;
        Ws[la_k + 2][la_r] = wv.z;
        Ws[la_k + 3][la_r] = wv.w;
        __syncthreads();
        #pragma unroll
        for (int kk = 0; kk < 16; ++kk) {
            float4 a = *(const float4*)&As[kk][cy * 4];
            float4 b = *(const float4*)&Ws[kk][cx * 4];
            acc[0][0] += a.x * b.x; acc[0][1] += a.x * b.y; acc[0][2] += a.x * b.z; acc[0][3] += a.x * b.w;
            acc[1][0] += a.y * b.x; acc[1][1] += a.y * b.y; acc[1][2] += a.y * b.z; acc[1][3] += a.y * b.w;
            acc[2][0] += a.z * b.x; acc[2][1] += a.z * b.y; acc[2][2] += a.z * b.z; acc[2][3] += a.z * b.w;
            acc[3][0] += a.w * b.x; acc[3][1] += a.w * b.y; acc[3][2] += a.w * b.z; acc[3][3] += a.w * b.w;
        }
        __syncthreads();
    }

    int col0 = n0 + cx * 4;
    #pragma unroll
    for (int i = 0; i < 4; ++i) {
        int r = cy * 4 + i;
        if (m0 + r >= mrows) continue;
        size_t crow = (size_t)(m_base + m0 + r);
        float vals[4];
        #pragma unroll
        for (int j = 0; j < 4; ++j) {
            float v = acc[i][j] + bias[col0 + j];
            if (act == 1) v = 0.5f * v * (1.0f + erff(v * 0.70710678118654752f));
            if (res) v += res[crow * N + col0 + j];
            vals[j] = v;
        }
        if (Cb) {
            ushort4 o;
            o.x = f2us(vals[0]); o.y = f2us(vals[1]);
            o.z = f2us(vals[2]); o.w = f2us(vals[3]);
            *(ushort4*)(Cb + crow * N + col0) = o;
        } else {
            *(float4*)(Cf + crow * N + col0) = make_float4(vals[0], vals[1], vals[2], vals[3]);
        }
    }
}

// ---------------- Attention: one wave per (b,h,q) row, online softmax ----------
// All operands are internal bf16 buffers.
__global__ __launch_bounds__(64) void attn_kernel(
    const bf16* __restrict__ Q, int ldq, int qoff,
    const bf16* __restrict__ KV, int ldk, int koff, int voff,
    bf16* __restrict__ O, int Lq, int Tk)
{
    int id = blockIdx.x;
    int q  = id % Lq;
    int h  = (id / Lq) % HH;
    int b  = id / (Lq * HH);
    int lane = threadIdx.x;

    __shared__ float qs[64];
    __shared__ float ps[64];

    const bf16* qrow = Q + (size_t)(b * Lq + q) * ldq + qoff + h * DHD;
    qs[lane] = toF(qrow[lane]);
    __syncthreads();

    float m = -INFINITY, l = 0.f, o = 0.f;
    const float scale = 0.125f;  // 1/sqrt(64)
    size_t kbase = (size_t)b * Tk * ldk;

    for (int t0 = 0; t0 < Tk; t0 += 64) {
        const bf16* kr = KV + kbase + (size_t)(t0 + lane) * ldk + koff + h * DHD;
        float s = 0.f;
        #pragma unroll
        for (int d4 = 0; d4 < 16; ++d4) {
            ushort4 kv4 = *(const ushort4*)(kr + d4 * 4);
            s += us2f(kv4.x) * qs[d4 * 4 + 0] + us2f(kv4.y) * qs[d4 * 4 + 1]
               + us2f(kv4.z) * qs[d4 * 4 + 2] + us2f(kv4.w) * qs[d4 * 4 + 3];
        }
        s *= scale;
        float cm = s;
        #pragma unroll
        for (int off = 32; off > 0; off >>= 1) cm = fmaxf(cm, __shfl_xor(cm, off));
        float nm = fmaxf(m, cm);
        float p = expf(s - nm);
        float cs = p;
        #pragma unroll
        for (int off = 32; off > 0; off >>= 1) cs += __shfl_xor(cs, off);
        float alpha = expf(m - nm);
        l = l * alpha + cs;
        __syncthreads();
        ps[lane] = p;
        __syncthreads();
        const bf16* vr = KV + kbase + (size_t)t0 * ldk + voff + h * DHD + lane;
        float pv = 0.f;
        #pragma unroll 8
        for (int j = 0; j < 64; ++j) pv += ps[j] * toF(vr[(size_t)j * ldk]);
        o = o * alpha + pv;
        m = nm;
    }
    O[(size_t)(b * Lq + q) * DD + h * DHD + lane] = __float2bfloat16(o / l);
}

// ---------------- MoE router: fp32 LN recomputed in-kernel ----------
// One wave per token. LN(X2) in fp32 -> 8 logits -> top-2 + gates.
// fp32 routing decisions match the numpy reference (no bf16 flip risk).
__global__ __launch_bounds__(64) void router_kernel(
    const float* __restrict__ X2,
    const float* __restrict__ g, const float* __restrict__ b,
    const float* __restrict__ rw, const float* __restrict__ rb,
    float* __restrict__ gates, int* __restrict__ ebuf, int* __restrict__ counts)
{
    int n = blockIdx.x;
    int lane = threadIdx.x;
    const float* xr = X2 + (size_t)n * DD;

    float v[16];
    #pragma unroll
    for (int i = 0; i < 16; ++i) v[i] = xr[lane + i * 64];

    float s = 0.f;
    #pragma unroll
    for (int i = 0; i < 16; ++i) s += v[i];
    #pragma unroll
    for (int off = 32; off > 0; off >>= 1) s += __shfl_xor(s, off);
    float mean = s * (1.0f / DD);

    float sq = 0.f;
    #pragma unroll
    for (int i = 0; i < 16; ++i) { float d = v[i] - mean; sq += d * d; }
    #pragma unroll
    for (int off = 32; off > 0; off >>= 1) sq += __shfl_xor(sq, off);
    float rstd = rsqrtf(sq * (1.0f / DD) + 1e-5f);

    float h[16];
    #pragma unroll
    for (int i = 0; i < 16; ++i) {
        int c = lane + i * 64;
        h[i] = (v[i] - mean) * rstd * g[c] + b[c];
    }

    float logit[EE];
    #pragma unroll
    for (int e = 0; e < EE; ++e) {
        const float* wr = rw + (size_t)e * DD;
        float p = 0.f;
        #pragma unroll
        for (int i = 0; i < 16; ++i) p += h[i] * wr[lane + i * 64];
        #pragma unroll
        for (int off = 32; off > 0; off >>= 1) p += __shfl_xor(p, off);
        logit[e] = p;
    }

    if (lane == 0) {
        #pragma unroll
        for (int e = 0; e < EE; ++e) logit[e] += rb[e];
        int i0 = 0;
        #pragma unroll
        for (int e = 1; e < EE; ++e) if (logit[e] > logit[i0]) i0 = e;
        int i1 = -1;
        #pragma unroll
        for (int e = 0; e < EE; ++e) {
            if (e == i0) continue;
            if (i1 < 0 || logit[e] > logit[i1]) i1 = e;
        }
        float ex = expf(logit[i1] - logit[i0]);
        float inv = 1.0f / (1.0f + ex);
        gates[2 * n + 0] = inv;
        gates[2 * n + 1] = ex * inv;
        ebuf[2 * n + 0] = i0;
        ebuf[2 * n + 1] = i1;
        atomicAdd(&counts[i0], 1);
        atomicAdd(&counts[i1], 1);
    }
}

__global__ void zero8_kernel(int* __restrict__ p) {
    if (threadIdx.x < EE) p[threadIdx.x] = 0;
}

__global__ void prefix_kernel(const int* __restrict__ counts,
                              int* __restrict__ seg_off, int* __restrict__ cursors) {
    if (threadIdx.x == 0) {
        int acc = 0;
        for (int e = 0; e < EE; ++e) { seg_off[e] = acc; cursors[e] = acc; acc += counts[e]; }
    }
}

__global__ __launch_bounds__(256) void scatter_kernel(
    const int* __restrict__ ebuf, int* __restrict__ cursors,
    int* __restrict__ tok_list, int* __restrict__ r_of)
{
    int n = blockIdx.x * 256 + threadIdx.x;
    if (n < NLAT) {
        for (int k = 0; k < 2; ++k) {
            int e = ebuf[2 * n + k];
            int r = atomicAdd(&cursors[e], 1);
            tok_list[r] = n;
            r_of[2 * n + k] = r;
        }
    }
}

__global__ __launch_bounds__(256) void mix_kernel(
    const float* __restrict__ X2, const bf16* __restrict__ EOUT,
    const float* __restrict__ gates, const int* __restrict__ r_of,
    float* __restrict__ out)
{
    int id = blockIdx.x * 256 + threadIdx.x;   // < NLAT*DD
    int n = id >> 10;
    int d = id & 1023;
    float v = X2[id]
            + gates[2 * n + 0] * toF(EOUT[(size_t)r_of[2 * n + 0] * DD + d])
            + gates[2 * n + 1] * toF(EOUT[(size_t)r_of[2 * n + 1] * DD + d]);
    out[id] = v;
}

// ---------------- Launcher ----------------
extern "C" void kernel_launch(void* const* d_in, const int* in_sizes, int n_in,
                              void* d_out, int out_size, void* d_ws, size_t ws_size,
                              hipStream_t stream)
{
    // ALL inputs are fp32 per the reference's setup_inputs (jnp.float32).
    const float* latents  = (const float*)d_in[0];
    const float* tokens   = (const float*)d_in[1];
    const float* sa_ln_g  = (const float*)d_in[2];
    const float* sa_ln_b  = (const float*)d_in[3];
    const float* sa_in_w  = (const float*)d_in[4];
    const float* sa_in_b  = (const float*)d_in[5];
    const float* sa_out_w = (const float*)d_in[6];
    const float* sa_out_b = (const float*)d_in[7];
    const float* ca_q_ln_g  = (const float*)d_in[8];
    const float* ca_q_ln_b  = (const float*)d_in[9];
    const float* ca_kv_ln_g = (const float*)d_in[10];
    const float* ca_kv_ln_b = (const float*)d_in[11];
    const float* ca_in_w  = (const float*)d_in[12];
    const float* ca_in_b  = (const float*)d_in[13];
    const float* ca_out_w = (const float*)d_in[14];
    const float* ca_out_b = (const float*)d_in[15];
    const float* moe_ln_g = (const float*)d_in[16];
    const float* moe_ln_b = (const float*)d_in[17];
    const float* router_w = (const float*)d_in[18];
    const float* router_b = (const float*)d_in[19];
    const float* e_fc1_w  = (const float*)d_in[20];
    const float* e_fc1_b  = (const float*)d_in[21];
    const float* e_fc2_w  = (const float*)d_in[22];
    const float* e_fc2_b  = (const float*)d_in[23];

    // ---- workspace layout (liveness-based reuse; peak ~76 MB) ----
    char* base = (char*)d_ws;
    const size_t MB = (size_t)1 << 20;
    float* X1   = (float*)(base + 0 * MB);   // [0,8)   fp32 2048x1024
    float* X2   = (float*)(base + 8 * MB);   // [8,16)  fp32 2048x1024
    bf16*  H    = (bf16*) (base + 16 * MB);  // [16,20) bf16 2048x1024 (LN out, reused 3x)
    bf16*  AO   = (bf16*) (base + 20 * MB);  // [20,24) bf16 2048x1024 (attn out, reused 2x)
    bf16*  QCA  = (bf16*) (base + 24 * MB);  // [24,28) bf16 2048x1024
    bf16*  KVLN = (bf16*) (base + 28 * MB);  // [28,44) bf16 8192x1024 (dead after CA-KV gemm)
    bf16*  EOUT = (bf16*) (base + 28 * MB);  // [28,36) bf16 4096x1024 (reuses KVLN)
    bf16*  KVCA = (bf16*) (base + 44 * MB);  // [44,76) bf16 8192x2048 (dead after CA attn)
    bf16*  QKV  = (bf16*) (base + 44 * MB);  // [44,56) bf16 2048x3072 (dead before KVCA write)
    bf16*  H1   = (bf16*) (base + 44 * MB);  // [44,76) bf16 4096x4096 (reuses KVCA)
    float* GATES = (float*)(base + 76 * MB); // 2048x2 fp32 = 16 KB
    int* ebuf     = (int*)(base + 76 * MB + 16384);
    int* tok_list = ebuf + NASG;
    int* r_of     = tok_list + NASG;
    int* counts   = r_of + NASG;
    int* seg_off  = counts + EE;
    int* cursors  = seg_off + EE;

    // 1. SA LN
    ln_kernel<<<NLAT, 256, 0, stream>>>(latents, sa_ln_g, sa_ln_b, H);
    // 2. SA QKV projection: [2048,1024] x [3072,1024]^T -> QKV bf16
    {
        dim3 g(3072 / 64, NLAT / 64, 1);
        gemm_kernel<<<g, 256, 0, stream>>>(H, sa_in_w, sa_in_b, QKV, nullptr,
                                           NLAT, 3072, DD,
                                           nullptr, 0, nullptr, nullptr, nullptr);
    }
    // 3. SA attention (K/V inside QKV, ld=3072)
    attn_kernel<<<BB * HH * LL, 64, 0, stream>>>(QKV, 3072, 0, QKV, 3072, 1024, 2048, AO, LL, LL);
    // 4. X1 = latents + AO @ sa_out_w^T + b   (fp32 out)
    {
        dim3 g(DD / 64, NLAT / 64, 1);
        gemm_kernel<<<g, 256, 0, stream>>>(AO, sa_out_w, sa_out_b, nullptr, X1,
                                           NLAT, DD, DD,
                                           latents, 0, nullptr, nullptr, nullptr);
    }
    // 5. CA q-LN (fp32 in, bf16 out)
    ln_kernel<<<NLAT, 256, 0, stream>>>(X1, ca_q_ln_g, ca_q_ln_b, H);
    // 6. CA kv-LN of tokens
    ln_kernel<<<NTOK, 256, 0, stream>>>(tokens, ca_kv_ln_g, ca_kv_ln_b, KVLN);
    // 7. CA Q projection (rows 0..1023 of ca_in_w)
    {
        dim3 g(DD / 64, NLAT / 64, 1);
        gemm_kernel<<<g, 256, 0, stream>>>(H, ca_in_w, ca_in_b, QCA, nullptr,
                                           NLAT, DD, DD,
                                           nullptr, 0, nullptr, nullptr, nullptr);
    }
    // 8. CA K,V projection (rows 1024..3071)
    {
        dim3 g(2048 / 64, NTOK / 64, 1);
        gemm_kernel<<<g, 256, 0, stream>>>(KVLN, ca_in_w + (size_t)1024 * DD, ca_in_b + 1024,
                                           KVCA, nullptr, NTOK, 2048, DD,
                                           nullptr, 0, nullptr, nullptr, nullptr);
    }
    // 9. CA attention
    attn_kernel<<<BB * HH * LL, 64, 0, stream>>>(QCA, 1024, 0, KVCA, 2048, 0, 1024, AO, LL, TT);
    // 10. X2 = X1 + AO @ ca_out_w^T + b  (fp32 out)
    {
        dim3 g(DD / 64, NLAT / 64, 1);
        gemm_kernel<<<g, 256, 0, stream>>>(AO, ca_out_w, ca_out_b, nullptr, X2,
                                           NLAT, DD, DD,
                                           X1, 0, nullptr, nullptr, nullptr);
    }
    // 11. MoE LN (bf16 H feeds the expert GEMMs; router re-does LN in fp32)
    ln_kernel<<<NLAT, 256, 0, stream>>>(X2, moe_ln_g, moe_ln_b, H);
    // 12-15. Routing (fp32-exact logits from X2)
    zero8_kernel<<<1, 64, 0, stream>>>(counts);
    router_kernel<<<NLAT, 64, 0, stream>>>(X2, moe_ln_g, moe_ln_b, router_w, router_b,
                                           GATES, ebuf, counts);
    prefix_kernel<<<1, 64, 0, stream>>>(counts, seg_off, cursors);
    scatter_kernel<<<NLAT / 256, 256, 0, stream>>>(ebuf, cursors, tok_list, r_of);
    // 16. fc1 grouped (gelu): rows gathered from H via tok_list
    {
        dim3 g(DFFD / 64, NLAT / 64, EE);
        gemm_kernel<<<g, 256, 0, stream>>>(H, e_fc1_w, e_fc1_b, H1, nullptr,
                                           0, DFFD, DD,
                                           nullptr, 1, tok_list, seg_off, counts);
    }
    // 17. fc2 grouped
    {
        dim3 g(DD / 64, NLAT / 64, EE);
        gemm_kernel<<<g, 256, 0, stream>>>(H1, e_fc2_w, e_fc2_b, EOUT, nullptr,
                                           0, DD, DFFD,
                                           nullptr, 0, nullptr, seg_off, counts);
    }
    // 18. Mix + residual -> fp32 out
    mix_kernel<<<(NLAT * DD) / 256, 256, 0, stream>>>(X2, EOUT, GATES, r_of, (float*)d_out);
}